// Round 15
// baseline (306.742 us; speedup 1.0000x reference)
//
#include <hip/hip_runtime.h>
#include <hip/hip_bf16.h>
#include <cmath>

constexpr int kB = 4;
constexpr int kS = 2048;
constexpr int kD = 1024;
constexpr int kH = 16;

typedef __attribute__((ext_vector_type(8))) short bf16x8;
typedef __attribute__((ext_vector_type(4))) float f32x4;
typedef __attribute__((ext_vector_type(4))) unsigned int u32x4;

__device__ __forceinline__ unsigned short f2bf(float f) {
  unsigned int u = __builtin_bit_cast(unsigned int, f);
  u = (u + 0x7fffu + ((u >> 16) & 1u)) >> 16;
  return (unsigned short)u;
}

__device__ __forceinline__ f32x4 mfma16(bf16x8 a, bf16x8 b, f32x4 c) {
  return __builtin_amdgcn_mfma_f32_16x16x32_bf16(a, b, c, 0, 0, 0);
}

#define GL16(gsrc, ldst)                                                      \
  __builtin_amdgcn_global_load_lds(                                           \
      (const __attribute__((address_space(1))) unsigned int*)(gsrc),          \
      (__attribute__((address_space(3))) unsigned int*)(ldst), 16, 0, 0)

#define CVTPK(dst, lo, hi)                                                    \
  asm("v_cvt_pk_bf16_f32 %0, %1, %2" : "=v"(dst) : "v"(lo), "v"(hi))

// Convert fp32 matrices -> bf16 k-major chunks via LDS transpose.
// k-major: chunk_g = (row>>7)*16384 + (k>>5)*512 + ((k>>3)&3)*128 + (row&127),
// 8 k-elems per chunk. y=0..3: weights Wq,Wk,Wv,Wo (1024 rows, 8 panels);
// y=4..6: inputs Q,K,V (8192 rows, 64 panels). One block = (panel, 64-k tile).
__global__ __launch_bounds__(256) void cvt_all(
    const float* __restrict__ w0, const float* __restrict__ w1,
    const float* __restrict__ w2, const float* __restrict__ w3,
    const float* __restrict__ x0, const float* __restrict__ x1,
    const float* __restrict__ x2,
    unsigned short* __restrict__ ow0, unsigned short* __restrict__ ow1,
    unsigned short* __restrict__ ow2, unsigned short* __restrict__ ow3,
    unsigned short* __restrict__ ox0, unsigned short* __restrict__ ox1,
    unsigned short* __restrict__ ox2) {
  const int y = blockIdx.y;
  if (y < 4 && blockIdx.x >= 128) return;   // weights: only 8 panels
  const float* src = y == 0 ? w0 : y == 1 ? w1 : y == 2 ? w2 : y == 3 ? w3
                   : y == 4 ? x0 : y == 5 ? x1 : x2;
  unsigned short* dst = y == 0 ? ow0 : y == 1 ? ow1 : y == 2 ? ow2 : y == 3 ? ow3
                      : y == 4 ? ox0 : y == 5 ? ox1 : ox2;
  __shared__ short Ls[128][72];   // 144B row stride: conflict-free transpose
  const int pn = blockIdx.x >> 4;    // panel
  const int t64 = blockIdx.x & 15;   // 64-k tile
  const int tid = threadIdx.x;

#pragma unroll
  for (int it = 0; it < 4; ++it) {
    const int u = it * 256 + tid;          // 0..1023
    const int row = u >> 3, k8 = u & 7;    // row 0..127, 8-float slice
    const float* s = src + (size_t)(pn * 128 + row) * kD + t64 * 64 + k8 * 8;
    float4 a = *reinterpret_cast<const float4*>(s);
    float4 b = *reinterpret_cast<const float4*>(s + 4);
    bf16x8 v;
    v[0] = (short)f2bf(a.x); v[1] = (short)f2bf(a.y);
    v[2] = (short)f2bf(a.z); v[3] = (short)f2bf(a.w);
    v[4] = (short)f2bf(b.x); v[5] = (short)f2bf(b.y);
    v[6] = (short)f2bf(b.z); v[7] = (short)f2bf(b.w);
    *reinterpret_cast<bf16x8*>(&Ls[row][k8 * 8]) = v;
  }
  __syncthreads();
#pragma unroll
  for (int it = 0; it < 4; ++it) {
    const int g = it * 256 + tid;
    const int ks8 = g >> 7, row = g & 127;
    bf16x8 v = *reinterpret_cast<const bf16x8*>(&Ls[row][ks8 * 8]);
    const size_t cg = (size_t)pn * 16384 + (size_t)(t64 * 2 + (ks8 >> 2)) * 512 +
                      (ks8 & 3) * 128 + row;
    *reinterpret_cast<bf16x8*>(dst + cg * 8) = v;
  }
}

// Fused Q/K/V projection GEMM. 256 threads (4 waves, 2Mx2N), 128x128 tile,
// BK=32, all-bf16 k-major operands, linear GL16 staging (conflict-free),
// 2-phase dbuf. launch_bounds(256,5): 5 blocks/CU (LDS 5x32KB = exactly
// 160KB) -> grid 1536 packs in 1.2 rounds instead of 1.5.
__global__ __launch_bounds__(256, 5) void proj_gemm6(
    const unsigned short* __restrict__ Xq, const unsigned short* __restrict__ Xk,
    const unsigned short* __restrict__ Xv,
    const unsigned short* __restrict__ Wq, const unsigned short* __restrict__ Wk,
    const unsigned short* __restrict__ Wv,
    const float* __restrict__ bq, const float* __restrict__ bk,
    const float* __restrict__ bv,
    unsigned short* __restrict__ oq, unsigned short* __restrict__ ok,
    unsigned short* __restrict__ ov) {
  const int vmode = blockIdx.z;
  const unsigned short* X = vmode == 0 ? Xq : vmode == 1 ? Xk : Xv;
  const unsigned short* Wb = vmode == 0 ? Wq : vmode == 1 ? Wk : Wv;
  const float* bias = vmode == 0 ? bq : vmode == 1 ? bk : bv;
  unsigned short* out = vmode == 0 ? oq : vmode == 1 ? ok : ov;
  const float scale = vmode == 0 ? 0.18033688f : 1.0f;

  __shared__ short Alds[2][4096];   // 8KB: 512 chunks
  __shared__ short Blds[2][4096];   // 8KB: 512 chunks
  const int tid = threadIdx.x;
  const int lane = tid & 63;
  const int w = tid >> 6;            // 0..3
  const int wr = w >> 1, wc = w & 1; // 2M x 2N, 64x64 per wave
  const int lg = lane >> 4, lc = lane & 15;
  const int pm = blockIdx.x;         // 128-row m-tile (0..63)
  const int pn = blockIdx.y;         // 128-col n-panel (0..7)

  auto stage = [&](int bs, int ks) {
#pragma unroll
    for (int it = 0; it < 2; ++it) {   // A: 512 chunks
      const int c = it * 256 + tid;
      GL16(X + ((size_t)pm * 16384 + (size_t)ks * 512 + c) * 8, &Alds[bs][c * 8]);
    }
#pragma unroll
    for (int it = 0; it < 2; ++it) {   // B: 512 chunks
      const int c = it * 256 + tid;
      GL16(Wb + ((size_t)pn * 16384 + (size_t)ks * 512 + c) * 8, &Blds[bs][c * 8]);
    }
  };

  f32x4 acc[4][4] = {};
  stage(0, 0);
  __syncthreads();
  int cur = 0;

  for (int ks = 0; ks < 32; ++ks) {
    if (ks + 1 < 32) stage(cur ^ 1, ks + 1);
    const short* Ac = &Alds[cur][0];
    const short* Bc = &Blds[cur][0];
    bf16x8 af[4], bfr[4];
#pragma unroll
    for (int mi = 0; mi < 4; ++mi)
      af[mi] = *reinterpret_cast<const bf16x8*>(
          Ac + (lg * 128 + wr * 64 + mi * 16 + lc) * 8);
#pragma unroll
    for (int ni = 0; ni < 4; ++ni)
      bfr[ni] = *reinterpret_cast<const bf16x8*>(
          Bc + (lg * 128 + wc * 64 + ni * 16 + lc) * 8);
    __builtin_amdgcn_s_setprio(1);
#pragma unroll
    for (int mi = 0; mi < 4; ++mi)
#pragma unroll
      for (int ni = 0; ni < 4; ++ni)
        acc[mi][ni] = mfma16(af[mi], bfr[ni], acc[mi][ni]);
    __builtin_amdgcn_s_setprio(0);
    __syncthreads();
    cur ^= 1;
  }

#pragma unroll
  for (int mi = 0; mi < 4; ++mi) {
#pragma unroll
    for (int ni = 0; ni < 4; ++ni) {
      const int n = pn * 128 + wc * 64 + ni * 16 + lc;
      const float bv = bias[n];
      const int h = n >> 6, dh = n & 63;
#pragma unroll
      for (int i = 0; i < 4; ++i) {
        const int m = pm * 128 + wr * 64 + mi * 16 + lg * 4 + i;
        const int b = m >> 11, s = m & 2047;
        const float v = (acc[mi][ni][i] + bv) * scale;
        size_t idx;
        if (vmode == 2)
          idx = ((size_t)((b * kH + h) * 256 + (s >> 3))) * 512 + (size_t)dh * 8 + (s & 7);
        else if (vmode == 1)
          idx = ((size_t)((b * kH + h) * kS + s)) * 64 +
                (((dh >> 3) ^ ((s & 3) | (((s >> 3) & 1) << 2))) << 3) + (dh & 7);
        else
          idx = ((size_t)((b * kH + h) * kS + s)) * 64 + dh;
        out[idx] = f2bf(v);
      }
    }
  }
}

// Flash attention, register-P permuted QK^T, static-max softmax, MFMA-pipe
// l-accumulation (unchanged from R13).
__global__ __launch_bounds__(256, 4) void attn_fwd(
    const unsigned short* __restrict__ qh,
    const unsigned short* __restrict__ khs,
    const unsigned short* __restrict__ vs,
    unsigned short* __restrict__ ctx) {
  __shared__ short Kb[2][4096];
  __shared__ short Vb[2][4096];

  const int tid = threadIdx.x;
  const int lane = tid & 63;
  const int w = tid >> 6;
  const int lg = lane >> 4, lc = lane & 15;
  const int bid = blockIdx.x;
  const int wg = (bid & 7) * 128 + (bid >> 3);
  const int qt = wg & 15;
  const int bh = wg >> 4;
  const int q0w = qt * 128 + w * 32;
  const size_t base = (size_t)bh * kS * 64;
  const int krl = 8 * (lc >> 2) + (lc & 3);
  const int kc = (lg ^ ((lc & 3) | (((lc >> 2) & 1) << 2))) << 3;

  const bf16x8 qa00 = *reinterpret_cast<const bf16x8*>(qh + base + (size_t)(q0w + lc) * 64 + lg * 8);
  const bf16x8 qa01 = *reinterpret_cast<const bf16x8*>(qh + base + (size_t)(q0w + lc) * 64 + 32 + lg * 8);
  const bf16x8 qa10 = *reinterpret_cast<const bf16x8*>(qh + base + (size_t)(q0w + 16 + lc) * 64 + lg * 8);
  const bf16x8 qa11 = *reinterpret_cast<const bf16x8*>(qh + base + (size_t)(q0w + 16 + lc) * 64 + 32 + lg * 8);

  f32x4 o0[4] = {}, o1[4] = {};
  f32x4 lacc0 = {}, lacc1 = {};   // MFMA-accumulated row-sums of P

  const u32x4 ones_u = {0x3F803F80u, 0x3F803F80u, 0x3F803F80u, 0x3F803F80u};
  const bf16x8 ones8 = __builtin_bit_cast(bf16x8, ones_u);

  auto stage = [&](int bset, int kv0) {
#pragma unroll
    for (int it = 0; it < 2; ++it) {
      const int cb = it * 256 + w * 64;
      GL16(khs + base + (size_t)kv0 * 64 + (size_t)(cb + lane) * 8, &Kb[bset][cb * 8]);
      GL16(vs + base + (size_t)kv0 * 64 + (size_t)(cb + lane) * 8, &Vb[bset][cb * 8]);
    }
  };

  stage(0, 0);
  __syncthreads();
  int cur = 0;

  const f32x4 cinit = {-4.f, -4.f, -4.f, -4.f};   // static softmax shift

  for (int t = 0; t < 32; ++t) {
    if (t + 1 < 32) stage(cur ^ 1, (t + 1) * 64);
    const short* Kc = &Kb[cur][0];
    const short* Vc = &Vb[cur][0];

#pragma unroll
    for (int kv32 = 0; kv32 < 64; kv32 += 32) {
      f32x4 s00, s01, s10, s11;
      __builtin_amdgcn_s_setprio(1);
      {
        const short* kr = Kc + (kv32 + krl) * 64;
        bf16x8 ka = *reinterpret_cast<const bf16x8*>(kr + kc);
        bf16x8 kb = *reinterpret_cast<const bf16x8*>(kr + (kc ^ 32));
        f32x4 z0 = cinit, z1 = cinit;
        z0 = mfma16(ka, qa00, z0); z0 = mfma16(kb, qa01, z0);
        z1 = mfma16(ka, qa10, z1); z1 = mfma16(kb, qa11, z1);
        s00 = z0; s10 = z1;
      }
      {
        const short* kr = Kc + (kv32 + krl + 4) * 64;
        bf16x8 ka = *reinterpret_cast<const bf16x8*>(kr + kc);
        bf16x8 kb = *reinterpret_cast<const bf16x8*>(kr + (kc ^ 32));
        f32x4 z0 = cinit, z1 = cinit;
        z0 = mfma16(ka, qa00, z0); z0 = mfma16(kb, qa01, z0);
        z1 = mfma16(ka, qa10, z1); z1 = mfma16(kb, qa11, z1);
        s01 = z0; s11 = z1;
      }
      __builtin_amdgcn_s_setprio(0);

      bf16x8 pa0, pa1;
      {
        float pA = __builtin_amdgcn_exp2f(s00[0]);
        float pB = __builtin_amdgcn_exp2f(s00[1]);
        float pC = __builtin_amdgcn_exp2f(s00[2]);
        float pD = __builtin_amdgcn_exp2f(s00[3]);
        float pE = __builtin_amdgcn_exp2f(s01[0]);
        float pF = __builtin_amdgcn_exp2f(s01[1]);
        float pG = __builtin_amdgcn_exp2f(s01[2]);
        float pH = __builtin_amdgcn_exp2f(s01[3]);
        unsigned uA, uB, uC, uD;
        CVTPK(uA, pA, pB); CVTPK(uB, pC, pD);
        CVTPK(uC, pE, pF); CVTPK(uD, pG, pH);
        u32x4 uu = {uA, uB, uC, uD};
        pa0 = __builtin_bit_cast(bf16x8, uu);
      }
      {
        float pA = __builtin_amdgcn_exp2f(s10[0]);
        float pB = __builtin_amdgcn_exp2f(s10[1]);
        float pC = __builtin_amdgcn_exp2f(s10[2]);
        float pD = __builtin_amdgcn_exp2f(s10[3]);
        float pE = __builtin_amdgcn_exp2f(s11[0]);
        float pF = __builtin_amdgcn_exp2f(s11[1]);
        float pG = __builtin_amdgcn_exp2f(s11[2]);
        float pH = __builtin_amdgcn_exp2f(s11[3]);
        unsigned uA, uB, uC, uD;
        CVTPK(uA, pA, pB); CVTPK(uB, pC, pD);
        CVTPK(uC, pE, pF); CVTPK(uD, pG, pH);
        u32x4 uu = {uA, uB, uC, uD};
        pa1 = __builtin_bit_cast(bf16x8, uu);
      }

      __builtin_amdgcn_s_setprio(1);
      lacc0 = mfma16(pa0, ones8, lacc0);
      lacc1 = mfma16(pa1, ones8, lacc1);
#pragma unroll
      for (int f = 0; f < 4; ++f) {
        bf16x8 vb = *reinterpret_cast<const bf16x8*>(
            Vc + ((kv32 >> 3) + lg) * 512 + (f * 16 + lc) * 8);
        o0[f] = mfma16(pa0, vb, o0[f]);
        o1[f] = mfma16(pa1, vb, o1[f]);
      }
      __builtin_amdgcn_s_setprio(0);
    }
    __syncthreads();
    cur ^= 1;
  }

  const int b = bh >> 4, h = bh & 15;
#pragma unroll
  for (int i = 0; i < 4; ++i) {
    const float inv0 = 1.0f / lacc0[i];   // rowsum(q=lg*4+i), no shuffles
    const float inv1 = 1.0f / lacc1[i];
    const int m0g = b * kS + q0w + lg * 4 + i;
    const int m1g = m0g + 16;
#pragma unroll
    for (int f = 0; f < 4; ++f) {
      const int d = h * 64 + f * 16 + lc;
      const size_t coff = (size_t)(d >> 5) * 512 + ((d >> 3) & 3) * 128;
      ctx[((size_t)(m0g >> 7) * 16384 + coff + (m0g & 127)) * 8 + (d & 7)] =
          f2bf(o0[f][i] * inv0);
      ctx[((size_t)(m1g >> 7) * 16384 + coff + (m1g & 127)) * 8 + (d & 7)] =
          f2bf(o1[f][i] * inv1);
    }
  }
}

// out[m][n] = sum_k ctx*Wo + bo, fp32 out. Ported to the proven 128x128
// 256-thread proj_gemm6 geometry (measured faster than 256x128/512-thr).
__global__ __launch_bounds__(256, 5) void oproj_gemm5(
    const unsigned short* __restrict__ A, const unsigned short* __restrict__ Wb,
    const float* __restrict__ bias, float* __restrict__ out) {
  __shared__ short Alds[2][4096];
  __shared__ short Blds[2][4096];
  const int tid = threadIdx.x;
  const int lane = tid & 63;
  const int w = tid >> 6;
  const int wr = w >> 1, wc = w & 1;
  const int lg = lane >> 4, lc = lane & 15;
  const int pm = blockIdx.x;   // 128-row m-tile (0..63)
  const int pn = blockIdx.y;   // 128-col n-panel (0..7)

  auto stage = [&](int bs, int ks) {
#pragma unroll
    for (int it = 0; it < 2; ++it) {
      const int c = it * 256 + tid;
      GL16(A + ((size_t)pm * 16384 + (size_t)ks * 512 + c) * 8, &Alds[bs][c * 8]);
    }
#pragma unroll
    for (int it = 0; it < 2; ++it) {
      const int c = it * 256 + tid;
      GL16(Wb + ((size_t)pn * 16384 + (size_t)ks * 512 + c) * 8, &Blds[bs][c * 8]);
    }
  };

  f32x4 acc[4][4] = {};
  stage(0, 0);
  __syncthreads();
  int cur = 0;

  for (int ks = 0; ks < 32; ++ks) {
    if (ks + 1 < 32) stage(cur ^ 1, ks + 1);
    const short* Ac = &Alds[cur][0];
    const short* Bc = &Blds[cur][0];
    bf16x8 af[4], bfr[4];
#pragma unroll
    for (int mi = 0; mi < 4; ++mi)
      af[mi] = *reinterpret_cast<const bf16x8*>(
          Ac + (lg * 128 + wr * 64 + mi * 16 + lc) * 8);
#pragma unroll
    for (int ni = 0; ni < 4; ++ni)
      bfr[ni] = *reinterpret_cast<const bf16x8*>(
          Bc + (lg * 128 + wc * 64 + ni * 16 + lc) * 8);
    __builtin_amdgcn_s_setprio(1);
#pragma unroll
    for (int mi = 0; mi < 4; ++mi)
#pragma unroll
      for (int ni = 0; ni < 4; ++ni)
        acc[mi][ni] = mfma16(af[mi], bfr[ni], acc[mi][ni]);
    __builtin_amdgcn_s_setprio(0);
    __syncthreads();
    cur ^= 1;
  }

#pragma unroll
  for (int mi = 0; mi < 4; ++mi) {
#pragma unroll
    for (int ni = 0; ni < 4; ++ni) {
      const int n = pn * 128 + wc * 64 + ni * 16 + lc;
      const float bv = bias[n];
#pragma unroll
      for (int i = 0; i < 4; ++i) {
        const long m = (long)pm * 128 + wr * 64 + mi * 16 + lg * 4 + i;
        out[(size_t)m * kD + n] = acc[mi][ni][i] + bv;
      }
    }
  }
}

extern "C" void kernel_launch(void* const* d_in, const int* in_sizes, int n_in,
                              void* d_out, int out_size, void* d_ws, size_t ws_size,
                              hipStream_t stream) {
  const float* Q  = (const float*)d_in[0];
  const float* K  = (const float*)d_in[1];
  const float* V  = (const float*)d_in[2];
  const float* Wq = (const float*)d_in[3];
  const float* bq = (const float*)d_in[4];
  const float* Wk = (const float*)d_in[5];
  const float* bk = (const float*)d_in[6];
  const float* Wv = (const float*)d_in[7];
  const float* bv = (const float*)d_in[8];
  const float* Wo = (const float*)d_in[9];
  const float* bo = (const float*)d_in[10];
  float* out = (float*)d_out;

  const size_t n_tok = (size_t)kB * kS * kD;   // 8388608
  const size_t n_w = (size_t)kD * kD;          // 1048576
  unsigned short* qh  = (unsigned short*)d_ws;
  unsigned short* kh  = qh + n_tok;
  unsigned short* vsw = kh + n_tok;
  unsigned short* xq  = vsw + n_tok;
  unsigned short* xk  = xq + n_tok;
  unsigned short* xv  = xk + n_tok;
  unsigned short* wqb = xv + n_tok;
  unsigned short* wkb = wqb + n_w;
  unsigned short* wvb = wkb + n_w;
  unsigned short* wob = wvb + n_w;
  unsigned short* cx  = xq;   // xq is dead after proj_gemm6; reuse for ctx

  dim3 b256(256, 1, 1);
  cvt_all<<<dim3(1024, 7, 1), b256, 0, stream>>>(Wq, Wk, Wv, Wo, Q, K, V,
                                                 wqb, wkb, wvb, wob, xq, xk, xv);
  proj_gemm6<<<dim3(64, 8, 3), b256, 0, stream>>>(xq, xk, xv, wqb, wkb, wvb,
                                                  bq, bk, bv, qh, kh, vsw);
  attn_fwd<<<dim3(1024, 1, 1), b256, 0, stream>>>(qh, kh, vsw, cx);
  oproj_gemm5<<<dim3(64, 8, 1), b256, 0, stream>>>(cx, wob, bo, out);
}

// Round 16
// 191.741 us; speedup vs baseline: 1.5998x; 1.5998x over previous
//
#include <hip/hip_runtime.h>
#include <hip/hip_bf16.h>
#include <cmath>

constexpr int kB = 4;
constexpr int kS = 2048;
constexpr int kD = 1024;
constexpr int kH = 16;

typedef __attribute__((ext_vector_type(8))) short bf16x8;
typedef __attribute__((ext_vector_type(4))) float f32x4;
typedef __attribute__((ext_vector_type(4))) unsigned int u32x4;

__device__ __forceinline__ unsigned short f2bf(float f) {
  unsigned int u = __builtin_bit_cast(unsigned int, f);
  u = (u + 0x7fffu + ((u >> 16) & 1u)) >> 16;
  return (unsigned short)u;
}

__device__ __forceinline__ f32x4 mfma16(bf16x8 a, bf16x8 b, f32x4 c) {
  return __builtin_amdgcn_mfma_f32_16x16x32_bf16(a, b, c, 0, 0, 0);
}

#define GL16(gsrc, ldst)                                                      \
  __builtin_amdgcn_global_load_lds(                                           \
      (const __attribute__((address_space(1))) unsigned int*)(gsrc),          \
      (__attribute__((address_space(3))) unsigned int*)(ldst), 16, 0, 0)

#define CVTPK(dst, lo, hi)                                                    \
  asm("v_cvt_pk_bf16_f32 %0, %1, %2" : "=v"(dst) : "v"(lo), "v"(hi))

// Convert fp32 matrices -> bf16 k-major chunks via LDS transpose.
// k-major: chunk_g = (row>>7)*16384 + (k>>5)*512 + ((k>>3)&3)*128 + (row&127),
// 8 k-elems per chunk. y=0..3: weights Wq,Wk,Wv,Wo (1024 rows, 8 panels);
// y=4..6: inputs Q,K,V (8192 rows, 64 panels). One block = (panel, 64-k tile).
__global__ __launch_bounds__(256) void cvt_all(
    const float* __restrict__ w0, const float* __restrict__ w1,
    const float* __restrict__ w2, const float* __restrict__ w3,
    const float* __restrict__ x0, const float* __restrict__ x1,
    const float* __restrict__ x2,
    unsigned short* __restrict__ ow0, unsigned short* __restrict__ ow1,
    unsigned short* __restrict__ ow2, unsigned short* __restrict__ ow3,
    unsigned short* __restrict__ ox0, unsigned short* __restrict__ ox1,
    unsigned short* __restrict__ ox2) {
  const int y = blockIdx.y;
  if (y < 4 && blockIdx.x >= 128) return;   // weights: only 8 panels
  const float* src = y == 0 ? w0 : y == 1 ? w1 : y == 2 ? w2 : y == 3 ? w3
                   : y == 4 ? x0 : y == 5 ? x1 : x2;
  unsigned short* dst = y == 0 ? ow0 : y == 1 ? ow1 : y == 2 ? ow2 : y == 3 ? ow3
                      : y == 4 ? ox0 : y == 5 ? ox1 : ox2;
  __shared__ short Ls[128][72];   // 144B row stride: conflict-free transpose
  const int pn = blockIdx.x >> 4;    // panel
  const int t64 = blockIdx.x & 15;   // 64-k tile
  const int tid = threadIdx.x;

#pragma unroll
  for (int it = 0; it < 4; ++it) {
    const int u = it * 256 + tid;          // 0..1023
    const int row = u >> 3, k8 = u & 7;    // row 0..127, 8-float slice
    const float* s = src + (size_t)(pn * 128 + row) * kD + t64 * 64 + k8 * 8;
    float4 a = *reinterpret_cast<const float4*>(s);
    float4 b = *reinterpret_cast<const float4*>(s + 4);
    bf16x8 v;
    v[0] = (short)f2bf(a.x); v[1] = (short)f2bf(a.y);
    v[2] = (short)f2bf(a.z); v[3] = (short)f2bf(a.w);
    v[4] = (short)f2bf(b.x); v[5] = (short)f2bf(b.y);
    v[6] = (short)f2bf(b.z); v[7] = (short)f2bf(b.w);
    *reinterpret_cast<bf16x8*>(&Ls[row][k8 * 8]) = v;
  }
  __syncthreads();
#pragma unroll
  for (int it = 0; it < 4; ++it) {
    const int g = it * 256 + tid;
    const int ks8 = g >> 7, row = g & 127;
    bf16x8 v = *reinterpret_cast<const bf16x8*>(&Ls[row][ks8 * 8]);
    const size_t cg = (size_t)pn * 16384 + (size_t)(t64 * 2 + (ks8 >> 2)) * 512 +
                      (ks8 & 3) * 128 + row;
    *reinterpret_cast<bf16x8*>(dst + cg * 8) = v;
  }
}

// Fused Q/K/V projection GEMM. 256 threads (4 waves, 2Mx2N), 128x128 tile,
// BK=32, all-bf16 k-major operands, linear GL16 staging (conflict-free),
// 2-phase dbuf. launch_bounds(256,4): (256,5) caused register spill
// (VGPR 60->48, WRITE_SIZE +67MB scratch, 2.5x slower) -- R14 lesson.
__global__ __launch_bounds__(256, 4) void proj_gemm6(
    const unsigned short* __restrict__ Xq, const unsigned short* __restrict__ Xk,
    const unsigned short* __restrict__ Xv,
    const unsigned short* __restrict__ Wq, const unsigned short* __restrict__ Wk,
    const unsigned short* __restrict__ Wv,
    const float* __restrict__ bq, const float* __restrict__ bk,
    const float* __restrict__ bv,
    unsigned short* __restrict__ oq, unsigned short* __restrict__ ok,
    unsigned short* __restrict__ ov) {
  const int vmode = blockIdx.z;
  const unsigned short* X = vmode == 0 ? Xq : vmode == 1 ? Xk : Xv;
  const unsigned short* Wb = vmode == 0 ? Wq : vmode == 1 ? Wk : Wv;
  const float* bias = vmode == 0 ? bq : vmode == 1 ? bk : bv;
  unsigned short* out = vmode == 0 ? oq : vmode == 1 ? ok : ov;
  const float scale = vmode == 0 ? 0.18033688f : 1.0f;

  __shared__ short Alds[2][4096];   // 8KB: 512 chunks
  __shared__ short Blds[2][4096];   // 8KB: 512 chunks
  const int tid = threadIdx.x;
  const int lane = tid & 63;
  const int w = tid >> 6;            // 0..3
  const int wr = w >> 1, wc = w & 1; // 2M x 2N, 64x64 per wave
  const int lg = lane >> 4, lc = lane & 15;
  const int pm = blockIdx.x;         // 128-row m-tile (0..63)
  const int pn = blockIdx.y;         // 128-col n-panel (0..7)

  auto stage = [&](int bs, int ks) {
#pragma unroll
    for (int it = 0; it < 2; ++it) {   // A: 512 chunks
      const int c = it * 256 + tid;
      GL16(X + ((size_t)pm * 16384 + (size_t)ks * 512 + c) * 8, &Alds[bs][c * 8]);
    }
#pragma unroll
    for (int it = 0; it < 2; ++it) {   // B: 512 chunks
      const int c = it * 256 + tid;
      GL16(Wb + ((size_t)pn * 16384 + (size_t)ks * 512 + c) * 8, &Blds[bs][c * 8]);
    }
  };

  f32x4 acc[4][4] = {};
  stage(0, 0);
  __syncthreads();
  int cur = 0;

  for (int ks = 0; ks < 32; ++ks) {
    if (ks + 1 < 32) stage(cur ^ 1, ks + 1);
    const short* Ac = &Alds[cur][0];
    const short* Bc = &Blds[cur][0];
    bf16x8 af[4], bfr[4];
#pragma unroll
    for (int mi = 0; mi < 4; ++mi)
      af[mi] = *reinterpret_cast<const bf16x8*>(
          Ac + (lg * 128 + wr * 64 + mi * 16 + lc) * 8);
#pragma unroll
    for (int ni = 0; ni < 4; ++ni)
      bfr[ni] = *reinterpret_cast<const bf16x8*>(
          Bc + (lg * 128 + wc * 64 + ni * 16 + lc) * 8);
    __builtin_amdgcn_s_setprio(1);
#pragma unroll
    for (int mi = 0; mi < 4; ++mi)
#pragma unroll
      for (int ni = 0; ni < 4; ++ni)
        acc[mi][ni] = mfma16(af[mi], bfr[ni], acc[mi][ni]);
    __builtin_amdgcn_s_setprio(0);
    __syncthreads();
    cur ^= 1;
  }

#pragma unroll
  for (int mi = 0; mi < 4; ++mi) {
#pragma unroll
    for (int ni = 0; ni < 4; ++ni) {
      const int n = pn * 128 + wc * 64 + ni * 16 + lc;
      const float bv = bias[n];
      const int h = n >> 6, dh = n & 63;
#pragma unroll
      for (int i = 0; i < 4; ++i) {
        const int m = pm * 128 + wr * 64 + mi * 16 + lg * 4 + i;
        const int b = m >> 11, s = m & 2047;
        const float v = (acc[mi][ni][i] + bv) * scale;
        size_t idx;
        if (vmode == 2)
          idx = ((size_t)((b * kH + h) * 256 + (s >> 3))) * 512 + (size_t)dh * 8 + (s & 7);
        else if (vmode == 1)
          idx = ((size_t)((b * kH + h) * kS + s)) * 64 +
                (((dh >> 3) ^ ((s & 3) | (((s >> 3) & 1) << 2))) << 3) + (dh & 7);
        else
          idx = ((size_t)((b * kH + h) * kS + s)) * 64 + dh;
        out[idx] = f2bf(v);
      }
    }
  }
}

// Flash attention, register-P permuted QK^T, static-max softmax, MFMA-pipe
// l-accumulation (unchanged from R13).
__global__ __launch_bounds__(256, 4) void attn_fwd(
    const unsigned short* __restrict__ qh,
    const unsigned short* __restrict__ khs,
    const unsigned short* __restrict__ vs,
    unsigned short* __restrict__ ctx) {
  __shared__ short Kb[2][4096];
  __shared__ short Vb[2][4096];

  const int tid = threadIdx.x;
  const int lane = tid & 63;
  const int w = tid >> 6;
  const int lg = lane >> 4, lc = lane & 15;
  const int bid = blockIdx.x;
  const int wg = (bid & 7) * 128 + (bid >> 3);
  const int qt = wg & 15;
  const int bh = wg >> 4;
  const int q0w = qt * 128 + w * 32;
  const size_t base = (size_t)bh * kS * 64;
  const int krl = 8 * (lc >> 2) + (lc & 3);
  const int kc = (lg ^ ((lc & 3) | (((lc >> 2) & 1) << 2))) << 3;

  const bf16x8 qa00 = *reinterpret_cast<const bf16x8*>(qh + base + (size_t)(q0w + lc) * 64 + lg * 8);
  const bf16x8 qa01 = *reinterpret_cast<const bf16x8*>(qh + base + (size_t)(q0w + lc) * 64 + 32 + lg * 8);
  const bf16x8 qa10 = *reinterpret_cast<const bf16x8*>(qh + base + (size_t)(q0w + 16 + lc) * 64 + lg * 8);
  const bf16x8 qa11 = *reinterpret_cast<const bf16x8*>(qh + base + (size_t)(q0w + 16 + lc) * 64 + 32 + lg * 8);

  f32x4 o0[4] = {}, o1[4] = {};
  f32x4 lacc0 = {}, lacc1 = {};   // MFMA-accumulated row-sums of P

  const u32x4 ones_u = {0x3F803F80u, 0x3F803F80u, 0x3F803F80u, 0x3F803F80u};
  const bf16x8 ones8 = __builtin_bit_cast(bf16x8, ones_u);

  auto stage = [&](int bset, int kv0) {
#pragma unroll
    for (int it = 0; it < 2; ++it) {
      const int cb = it * 256 + w * 64;
      GL16(khs + base + (size_t)kv0 * 64 + (size_t)(cb + lane) * 8, &Kb[bset][cb * 8]);
      GL16(vs + base + (size_t)kv0 * 64 + (size_t)(cb + lane) * 8, &Vb[bset][cb * 8]);
    }
  };

  stage(0, 0);
  __syncthreads();
  int cur = 0;

  const f32x4 cinit = {-4.f, -4.f, -4.f, -4.f};   // static softmax shift

  for (int t = 0; t < 32; ++t) {
    if (t + 1 < 32) stage(cur ^ 1, (t + 1) * 64);
    const short* Kc = &Kb[cur][0];
    const short* Vc = &Vb[cur][0];

#pragma unroll
    for (int kv32 = 0; kv32 < 64; kv32 += 32) {
      f32x4 s00, s01, s10, s11;
      __builtin_amdgcn_s_setprio(1);
      {
        const short* kr = Kc + (kv32 + krl) * 64;
        bf16x8 ka = *reinterpret_cast<const bf16x8*>(kr + kc);
        bf16x8 kb = *reinterpret_cast<const bf16x8*>(kr + (kc ^ 32));
        f32x4 z0 = cinit, z1 = cinit;
        z0 = mfma16(ka, qa00, z0); z0 = mfma16(kb, qa01, z0);
        z1 = mfma16(ka, qa10, z1); z1 = mfma16(kb, qa11, z1);
        s00 = z0; s10 = z1;
      }
      {
        const short* kr = Kc + (kv32 + krl + 4) * 64;
        bf16x8 ka = *reinterpret_cast<const bf16x8*>(kr + kc);
        bf16x8 kb = *reinterpret_cast<const bf16x8*>(kr + (kc ^ 32));
        f32x4 z0 = cinit, z1 = cinit;
        z0 = mfma16(ka, qa00, z0); z0 = mfma16(kb, qa01, z0);
        z1 = mfma16(ka, qa10, z1); z1 = mfma16(kb, qa11, z1);
        s01 = z0; s11 = z1;
      }
      __builtin_amdgcn_s_setprio(0);

      bf16x8 pa0, pa1;
      {
        float pA = __builtin_amdgcn_exp2f(s00[0]);
        float pB = __builtin_amdgcn_exp2f(s00[1]);
        float pC = __builtin_amdgcn_exp2f(s00[2]);
        float pD = __builtin_amdgcn_exp2f(s00[3]);
        float pE = __builtin_amdgcn_exp2f(s01[0]);
        float pF = __builtin_amdgcn_exp2f(s01[1]);
        float pG = __builtin_amdgcn_exp2f(s01[2]);
        float pH = __builtin_amdgcn_exp2f(s01[3]);
        unsigned uA, uB, uC, uD;
        CVTPK(uA, pA, pB); CVTPK(uB, pC, pD);
        CVTPK(uC, pE, pF); CVTPK(uD, pG, pH);
        u32x4 uu = {uA, uB, uC, uD};
        pa0 = __builtin_bit_cast(bf16x8, uu);
      }
      {
        float pA = __builtin_amdgcn_exp2f(s10[0]);
        float pB = __builtin_amdgcn_exp2f(s10[1]);
        float pC = __builtin_amdgcn_exp2f(s10[2]);
        float pD = __builtin_amdgcn_exp2f(s10[3]);
        float pE = __builtin_amdgcn_exp2f(s11[0]);
        float pF = __builtin_amdgcn_exp2f(s11[1]);
        float pG = __builtin_amdgcn_exp2f(s11[2]);
        float pH = __builtin_amdgcn_exp2f(s11[3]);
        unsigned uA, uB, uC, uD;
        CVTPK(uA, pA, pB); CVTPK(uB, pC, pD);
        CVTPK(uC, pE, pF); CVTPK(uD, pG, pH);
        u32x4 uu = {uA, uB, uC, uD};
        pa1 = __builtin_bit_cast(bf16x8, uu);
      }

      __builtin_amdgcn_s_setprio(1);
      lacc0 = mfma16(pa0, ones8, lacc0);
      lacc1 = mfma16(pa1, ones8, lacc1);
#pragma unroll
      for (int f = 0; f < 4; ++f) {
        bf16x8 vb = *reinterpret_cast<const bf16x8*>(
            Vc + ((kv32 >> 3) + lg) * 512 + (f * 16 + lc) * 8);
        o0[f] = mfma16(pa0, vb, o0[f]);
        o1[f] = mfma16(pa1, vb, o1[f]);
      }
      __builtin_amdgcn_s_setprio(0);
    }
    __syncthreads();
    cur ^= 1;
  }

  const int b = bh >> 4, h = bh & 15;
#pragma unroll
  for (int i = 0; i < 4; ++i) {
    const float inv0 = 1.0f / lacc0[i];   // rowsum(q=lg*4+i), no shuffles
    const float inv1 = 1.0f / lacc1[i];
    const int m0g = b * kS + q0w + lg * 4 + i;
    const int m1g = m0g + 16;
#pragma unroll
    for (int f = 0; f < 4; ++f) {
      const int d = h * 64 + f * 16 + lc;
      const size_t coff = (size_t)(d >> 5) * 512 + ((d >> 3) & 3) * 128;
      ctx[((size_t)(m0g >> 7) * 16384 + coff + (m0g & 127)) * 8 + (d & 7)] =
          f2bf(o0[f][i] * inv0);
      ctx[((size_t)(m1g >> 7) * 16384 + coff + (m1g & 127)) * 8 + (d & 7)] =
          f2bf(o1[f][i] * inv1);
    }
  }
}

// out[m][n] = sum_k ctx*Wo + bo, fp32 out. 128x128 / 256-thread geometry,
// launch_bounds(256,4) (the (256,5) cap caused spills -- R14).
__global__ __launch_bounds__(256, 4) void oproj_gemm5(
    const unsigned short* __restrict__ A, const unsigned short* __restrict__ Wb,
    const float* __restrict__ bias, float* __restrict__ out) {
  __shared__ short Alds[2][4096];
  __shared__ short Blds[2][4096];
  const int tid = threadIdx.x;
  const int lane = tid & 63;
  const int w = tid >> 6;
  const int wr = w >> 1, wc = w & 1;
  const int lg = lane >> 4, lc = lane & 15;
  const int pm = blockIdx.x;   // 128-row m-tile (0..63)
  const int pn = blockIdx.y;   // 128-col n-panel (0..7)

  auto stage = [&](int bs, int ks) {
#pragma unroll
    for (int it = 0; it < 2; ++it) {
      const int c = it * 256 + tid;
      GL16(A + ((size_t)pm * 16384 + (size_t)ks * 512 + c) * 8, &Alds[bs][c * 8]);
    }
#pragma unroll
    for (int it = 0; it < 2; ++it) {
      const int c = it * 256 + tid;
      GL16(Wb + ((size_t)pn * 16384 + (size_t)ks * 512 + c) * 8, &Blds[bs][c * 8]);
    }
  };

  f32x4 acc[4][4] = {};
  stage(0, 0);
  __syncthreads();
  int cur = 0;

  for (int ks = 0; ks < 32; ++ks) {
    if (ks + 1 < 32) stage(cur ^ 1, ks + 1);
    const short* Ac = &Alds[cur][0];
    const short* Bc = &Blds[cur][0];
    bf16x8 af[4], bfr[4];
#pragma unroll
    for (int mi = 0; mi < 4; ++mi)
      af[mi] = *reinterpret_cast<const bf16x8*>(
          Ac + (lg * 128 + wr * 64 + mi * 16 + lc) * 8);
#pragma unroll
    for (int ni = 0; ni < 4; ++ni)
      bfr[ni] = *reinterpret_cast<const bf16x8*>(
          Bc + (lg * 128 + wc * 64 + ni * 16 + lc) * 8);
    __builtin_amdgcn_s_setprio(1);
#pragma unroll
    for (int mi = 0; mi < 4; ++mi)
#pragma unroll
      for (int ni = 0; ni < 4; ++ni)
        acc[mi][ni] = mfma16(af[mi], bfr[ni], acc[mi][ni]);
    __builtin_amdgcn_s_setprio(0);
    __syncthreads();
    cur ^= 1;
  }

#pragma unroll
  for (int mi = 0; mi < 4; ++mi) {
#pragma unroll
    for (int ni = 0; ni < 4; ++ni) {
      const int n = pn * 128 + wc * 64 + ni * 16 + lc;
      const float bv = bias[n];
#pragma unroll
      for (int i = 0; i < 4; ++i) {
        const long m = (long)pm * 128 + wr * 64 + mi * 16 + lg * 4 + i;
        out[(size_t)m * kD + n] = acc[mi][ni][i] + bv;
      }
    }
  }
}

extern "C" void kernel_launch(void* const* d_in, const int* in_sizes, int n_in,
                              void* d_out, int out_size, void* d_ws, size_t ws_size,
                              hipStream_t stream) {
  const float* Q  = (const float*)d_in[0];
  const float* K  = (const float*)d_in[1];
  const float* V  = (const float*)d_in[2];
  const float* Wq = (const float*)d_in[3];
  const float* bq = (const float*)d_in[4];
  const float* Wk = (const float*)d_in[5];
  const float* bk = (const float*)d_in[6];
  const float* Wv = (const float*)d_in[7];
  const float* bv = (const float*)d_in[8];
  const float* Wo = (const float*)d_in[9];
  const float* bo = (const float*)d_in[10];
  float* out = (float*)d_out;

  const size_t n_tok = (size_t)kB * kS * kD;   // 8388608
  const size_t n_w = (size_t)kD * kD;          // 1048576
  unsigned short* qh  = (unsigned short*)d_ws;
  unsigned short* kh  = qh + n_tok;
  unsigned short* vsw = kh + n_tok;
  unsigned short* xq  = vsw + n_tok;
  unsigned short* xk  = xq + n_tok;
  unsigned short* xv  = xk + n_tok;
  unsigned short* wqb = xv + n_tok;
  unsigned short* wkb = wqb + n_w;
  unsigned short* wvb = wkb + n_w;
  unsigned short* wob = wvb + n_w;
  unsigned short* cx  = xq;   // xq is dead after proj_gemm6; reuse for ctx

  dim3 b256(256, 1, 1);
  cvt_all<<<dim3(1024, 7, 1), b256, 0, stream>>>(Wq, Wk, Wv, Wo, Q, K, V,
                                                 wqb, wkb, wvb, wob, xq, xk, xv);
  proj_gemm6<<<dim3(64, 8, 3), b256, 0, stream>>>(xq, xk, xv, wqb, wkb, wvb,
                                                  bq, bk, bv, qh, kh, vsw);
  attn_fwd<<<dim3(1024, 1, 1), b256, 0, stream>>>(qh, kh, vsw, cx);
  oproj_gemm5<<<dim3(64, 8, 1), b256, 0, stream>>>(cx, wob, bo, out);
}